// Round 13
// baseline (455.450 us; speedup 1.0000x reference)
//
#include <hip/hip_runtime.h>
#include <math.h>

#define IN_DIM 128
#define OUT_DIM 64
#define BKT 256      // dst-nodes per bucket
#define CHUNK 4096   // edges per binning block
#define NBMAX 512

typedef __attribute__((ext_vector_type(8))) short short8;
typedef __attribute__((ext_vector_type(4))) float f32x4;
typedef __attribute__((ext_vector_type(2))) float f32x2;

__device__ __forceinline__ ushort f2bf(float f) {
    uint u = __float_as_uint(f);
    u += 0x7FFF + ((u >> 16) & 1);   // round-to-nearest-even
    return (ushort)(u >> 16);
}
__device__ __forceinline__ float bf2f(ushort h) {
    return __uint_as_float(((uint)h) << 16);
}
__device__ __forceinline__ uchar f2fp8(float v) {
    return (uchar)(__builtin_amdgcn_cvt_pk_fp8_f32(v, v, 0, false) & 0xFF);
}

// ---------------- pack W[K=128][N] fp32 -> MFMA B-fragment order bf16 ----------------
__device__ __forceinline__ void packw_body(const float* __restrict__ W, ushort* __restrict__ Bp,
                                           int idx, int N) {
    int e = idx & 7;
    int lane = (idx >> 3) & 63;
    int rest = idx >> 9;
    int nt = rest % (N / 16);
    int kk = rest / (N / 16);
    int k = kk * 32 + (lane >> 4) * 8 + e;
    int n = nt * 16 + (lane & 15);
    Bp[idx] = f2bf(W[k * N + n]);
}

// ---------------- B1: per-block bucket histogram (stored, no atomics) || packw ------
__global__ __launch_bounds__(256) void b1_kernel(const int* __restrict__ dst,
                                                 int* __restrict__ blkhist,
                                                 const float* __restrict__ W1,
                                                 ushort* __restrict__ W1p,
                                                 const float* __restrict__ W2,
                                                 ushort* __restrict__ W2p,
                                                 int E, int nb, int nbBin) {
    __shared__ int lh[NBMAX];
    int b = blockIdx.x, t = threadIdx.x;
    if (b < nbBin) {
        for (int i = t; i < nb; i += 256) lh[i] = 0;
        __syncthreads();
        int base = b * CHUNK;
#pragma unroll
        for (int i = 0; i < CHUNK / 256; ++i) {
            int e = base + i * 256 + t;
            if (e < E) atomicAdd(&lh[((uint)dst[e]) >> 8], 1);
        }
        __syncthreads();
        for (int i = t; i < nb; i += 256) blkhist[b * nb + i] = lh[i];
    } else if (b < nbBin + 64) {
        packw_body(W1, W1p, (b - nbBin) * 256 + t, 128);      // 128*128
    } else {
        packw_body(W2, W2p, (b - nbBin - 64) * 256 + t, 64);  // 128*64
    }
}

// ---------------- B2: scan blkhist -> exact per-(block,bucket) offsets --------------
// thread t owns bucket t; two serial passes over nbBin blocks (coalesced rows)
__global__ __launch_bounds__(512) void b2_kernel(const int* __restrict__ blkhist,
                                                 int* __restrict__ blkoff,
                                                 int* __restrict__ bucket_off,
                                                 float* __restrict__ out,
                                                 int nb, int nbBin) {
    __shared__ int s[512];
    int t = threadIdx.x;
    if (t < OUT_DIM) out[t] = 0.0f;
    int tot = 0;
    if (t < nb)
        for (int b = 0; b < nbBin; ++b) tot += blkhist[b * nb + t];
    s[t] = tot;
    __syncthreads();
    for (int off = 1; off < 512; off <<= 1) {
        int add = (t >= off) ? s[t - off] : 0;
        __syncthreads();
        s[t] += add;
        __syncthreads();
    }
    int excl = s[t] - tot;
    if (t < nb) bucket_off[t] = excl;
    if (t == 511) bucket_off[nb] = s[511];   // = E
    if (t < nb) {
        int run = excl;
        for (int b = 0; b < nbBin; ++b) {
            blkoff[b * nb + t] = run;
            run += blkhist[b * nb + t];
        }
    }
}

// ---------------- B3: single-pass bin scatter || MFMA gemm1 -> fp8 H1 ----------
__global__ __launch_bounds__(256) void b3_kernel(const int* __restrict__ src,
                                                 const int* __restrict__ dst,
                                                 const int* __restrict__ blkoff,
                                                 uint* __restrict__ pairs,
                                                 const float* __restrict__ X,
                                                 const ushort* __restrict__ Bp,
                                                 uchar* __restrict__ H1,
                                                 int E, int M, int nb, int nbBin) {
    __shared__ int lf[NBMAX];
    int b = blockIdx.x, t = threadIdx.x;
    if (b < nbBin) {
        for (int i = t; i < nb; i += 256) lf[i] = blkoff[b * nb + i];
        __syncthreads();
        int base = b * CHUNK;
#pragma unroll
        for (int i = 0; i < CHUNK / 256; ++i) {
            int e = base + i * 256 + t;
            if (e < E) {
                int d = dst[e];
                int r = atomicAdd(&lf[((uint)d) >> 8], 1);
                pairs[r] = (((uint)src[e]) << 8) | ((uint)d & 255);  // src < 2^24
            }
        }
        return;
    }
    // ---- gemm1: H1[M][128] = fp8( X[M][128] @ W1 )  (unscaled; prescaled later in b4) ----
    int wid = t >> 6, lane = t & 63;
    int rowBase = ((b - nbBin) * 4 + wid) * 16;
    if (rowBase >= M) return;
    int m = lane & 15, kg = lane >> 4;
    const float* arow = X + (size_t)(rowBase + m) * 128 + kg * 8;
    short8 af[4];
#pragma unroll
    for (int kk = 0; kk < 4; ++kk) {
        float4 a0 = *(const float4*)(arow + kk * 32);
        float4 a1 = *(const float4*)(arow + kk * 32 + 4);
        short8 v;
        v[0] = (short)f2bf(a0.x); v[1] = (short)f2bf(a0.y);
        v[2] = (short)f2bf(a0.z); v[3] = (short)f2bf(a0.w);
        v[4] = (short)f2bf(a1.x); v[5] = (short)f2bf(a1.y);
        v[6] = (short)f2bf(a1.z); v[7] = (short)f2bf(a1.w);
        af[kk] = v;
    }
#pragma unroll
    for (int nt = 0; nt < 8; ++nt) {
        f32x4 acc = {0.f, 0.f, 0.f, 0.f};
#pragma unroll
        for (int kk = 0; kk < 4; ++kk) {
            short8 bf = *reinterpret_cast<const short8*>(Bp + ((size_t)(kk * 8 + nt) * 64 + lane) * 8);
            acc = __builtin_amdgcn_mfma_f32_16x16x32_bf16(af[kk], bf, acc, 0, 0, 0);
        }
        int col = nt * 16 + m;
#pragma unroll
        for (int r = 0; r < 4; ++r) {
            int row = rowBase + kg * 4 + r;
            H1[(size_t)row * 128 + col] = f2fp8(acc[r]);
        }
    }
}

// ---------------- B4: per-bucket CSR finalize + in-place dinv-prescale of H1 ----------
__global__ __launch_bounds__(256) void b4_kernel(const uint* __restrict__ pairs,
                                                 const int* __restrict__ bucket_off,
                                                 int* __restrict__ rowptr,
                                                 float* __restrict__ dinv,
                                                 int* __restrict__ srcs,
                                                 uchar* __restrict__ H1,
                                                 int n, int E, int nb) {
    __shared__ int lcnt[BKT];
    __shared__ int ls[BKT];
    __shared__ int lfill[BKT];
    __shared__ float sdv[BKT];
    int b = blockIdx.x, t = threadIdx.x;
    int base = b * BKT;
    int bs = min(BKT, n - base);
    int estart = bucket_off[b], eend = bucket_off[b + 1];
    lcnt[t] = 0;
    __syncthreads();
    for (int e = estart + t; e < eend; e += 256)
        atomicAdd(&lcnt[pairs[e] & 255], 1);
    __syncthreads();
    int v = lcnt[t];
    ls[t] = v;
    __syncthreads();
    for (int off = 1; off < 256; off <<= 1) {
        int add = (t >= off) ? ls[t - off] : 0;
        __syncthreads();
        ls[t] += add;
        __syncthreads();
    }
    int excl = ls[t] - v;
    lfill[t] = excl;
    float dvt = rsqrtf((float)(v + 1));   // +1 self loop
    sdv[t] = dvt;
    if (t < bs) {
        rowptr[base + t] = estart + excl;
        dinv[base + t] = dvt;
    }
    if (b == nb - 1 && t == 0) rowptr[n] = E;
    __syncthreads();
    for (int e = estart + t; e < eend; e += 256) {
        uint p = pairs[e];
        int pos = atomicAdd(&lfill[p & 255], 1);
        srcs[estart + pos] = (int)(p >> 8);
    }
    // ---- in-place prescale: H1[base..base+bs) *= dinv[node] (fp8 RMW, exclusive range) ----
    uint* Hrow = (uint*)(H1 + (size_t)base * 128);
    int total_u = bs * 32;                // 32 uints per 128B row
    for (int u = t; u < total_u; u += 256) {
        float s = sdv[u >> 5];
        uint w = Hrow[u];
        f32x2 lo = __builtin_amdgcn_cvt_pk_f32_fp8((int)w, false);
        f32x2 hi = __builtin_amdgcn_cvt_pk_f32_fp8((int)w, true);
        int ow = __builtin_amdgcn_cvt_pk_fp8_f32(lo[0] * s, lo[1] * s, 0, false);
        ow = __builtin_amdgcn_cvt_pk_fp8_f32(hi[0] * s, hi[1] * s, ow, true);
        Hrow[u] = (uint)ow;
    }
}

// ---------------- gemm2: H2[M][64] = fp8( dinv[row] * (h1[M][128] @ W2) ) ------------
__global__ __launch_bounds__(256) void gemm2_kernel(const ushort* __restrict__ A,
                                                    const ushort* __restrict__ Bp,
                                                    const float* __restrict__ dinv,
                                                    uchar* __restrict__ Out, int M) {
    int wid = threadIdx.x >> 6, lane = threadIdx.x & 63;
    int rowBase = (blockIdx.x * 4 + wid) * 16;
    if (rowBase >= M) return;
    int m = lane & 15, kg = lane >> 4;
    const ushort* arow = A + (size_t)(rowBase + m) * 128 + kg * 8;
    short8 af[4];
#pragma unroll
    for (int kk = 0; kk < 4; ++kk)
        af[kk] = *reinterpret_cast<const short8*>(arow + kk * 32);
    float dv[4];
#pragma unroll
    for (int r = 0; r < 4; ++r) dv[r] = dinv[rowBase + kg * 4 + r];
#pragma unroll
    for (int nt = 0; nt < 4; ++nt) {
        f32x4 acc = {0.f, 0.f, 0.f, 0.f};
#pragma unroll
        for (int kk = 0; kk < 4; ++kk) {
            short8 bf = *reinterpret_cast<const short8*>(
                Bp + ((size_t)(kk * 4 + nt) * 64 + lane) * 8);
            acc = __builtin_amdgcn_mfma_f32_16x16x32_bf16(af[kk], bf, acc, 0, 0, 0);
        }
        int col = nt * 16 + m;
#pragma unroll
        for (int r = 0; r < 4; ++r) {
            int row = rowBase + kg * 4 + r;
            Out[(size_t)row * 64 + col] = f2fp8(acc[r] * dv[r]);
        }
    }
}

// ---------------- layer-1 agg: quarter-wave uint2 fp8 gather, tail-split, relu ------
// h1[v] = relu( dv * ( H1s[v] + sum_s H1s[s] ) + b1 ),  4 edges per VMEM instruction
__global__ __launch_bounds__(256) void agg1_kernel(const uchar* __restrict__ Hs,
                                                   ushort* __restrict__ Hout,
                                                   const int* __restrict__ rowptr,
                                                   const int* __restrict__ srcs,
                                                   const float* __restrict__ dinv,
                                                   const float* __restrict__ bias, int n) {
    int wv = __builtin_amdgcn_readfirstlane(threadIdx.x) >> 6;
    int lane = threadIdx.x & 63;
    int node = blockIdx.x * 4 + wv;
    if (node >= n) return;
    int q = lane >> 4, c = lane & 15;
    float dv = dinv[node];
    int start = rowptr[node], end = rowptr[node + 1];
    float a0 = 0.f, a1 = 0.f, a2 = 0.f, a3 = 0.f, a4 = 0.f, a5 = 0.f, a6 = 0.f, a7 = 0.f;
    if (q == 0) {
        uint2 s = ((const uint2*)(Hs + (size_t)node * 128))[c];
        f32x2 p0 = __builtin_amdgcn_cvt_pk_f32_fp8((int)s.x, false);
        f32x2 p1 = __builtin_amdgcn_cvt_pk_f32_fp8((int)s.x, true);
        f32x2 p2 = __builtin_amdgcn_cvt_pk_f32_fp8((int)s.y, false);
        f32x2 p3 = __builtin_amdgcn_cvt_pk_f32_fp8((int)s.y, true);
        a0 = p0[0]; a1 = p0[1]; a2 = p1[0]; a3 = p1[1];
        a4 = p2[0]; a5 = p2[1]; a6 = p3[0]; a7 = p3[1];
    }
    int deg = end - start;
    int full = start + (deg & ~3);
    for (int j = start; j < full; j += 4) {     // full rounds: no masks, no clamps
        int sj = srcs[j + q];
        uint2 v = ((const uint2*)(Hs + (size_t)sj * 128))[c];
        f32x2 p0 = __builtin_amdgcn_cvt_pk_f32_fp8((int)v.x, false);
        f32x2 p1 = __builtin_amdgcn_cvt_pk_f32_fp8((int)v.x, true);
        f32x2 p2 = __builtin_amdgcn_cvt_pk_f32_fp8((int)v.y, false);
        f32x2 p3 = __builtin_amdgcn_cvt_pk_f32_fp8((int)v.y, true);
        a0 += p0[0]; a1 += p0[1]; a2 += p1[0]; a3 += p1[1];
        a4 += p2[0]; a5 += p2[1]; a6 += p3[0]; a7 += p3[1];
    }
    if (deg & 3) {                               // single masked tail round
        int jj = full + q;
        int sj = srcs[min(jj, end - 1)];
        float w = (jj < end) ? 1.0f : 0.0f;
        uint2 v = ((const uint2*)(Hs + (size_t)sj * 128))[c];
        f32x2 p0 = __builtin_amdgcn_cvt_pk_f32_fp8((int)v.x, false);
        f32x2 p1 = __builtin_amdgcn_cvt_pk_f32_fp8((int)v.x, true);
        f32x2 p2 = __builtin_amdgcn_cvt_pk_f32_fp8((int)v.y, false);
        f32x2 p3 = __builtin_amdgcn_cvt_pk_f32_fp8((int)v.y, true);
        a0 = fmaf(w, p0[0], a0); a1 = fmaf(w, p0[1], a1);
        a2 = fmaf(w, p1[0], a2); a3 = fmaf(w, p1[1], a3);
        a4 = fmaf(w, p2[0], a4); a5 = fmaf(w, p2[1], a5);
        a6 = fmaf(w, p3[0], a6); a7 = fmaf(w, p3[1], a7);
    }
    a0 += __shfl_xor(a0, 16); a1 += __shfl_xor(a1, 16);
    a2 += __shfl_xor(a2, 16); a3 += __shfl_xor(a3, 16);
    a4 += __shfl_xor(a4, 16); a5 += __shfl_xor(a5, 16);
    a6 += __shfl_xor(a6, 16); a7 += __shfl_xor(a7, 16);
    a0 += __shfl_xor(a0, 32); a1 += __shfl_xor(a1, 32);
    a2 += __shfl_xor(a2, 32); a3 += __shfl_xor(a3, 32);
    a4 += __shfl_xor(a4, 32); a5 += __shfl_xor(a5, 32);
    a6 += __shfl_xor(a6, 32); a7 += __shfl_xor(a7, 32);
    if (q == 0) {
        float4 b0 = *(const float4*)(bias + 8 * c);
        float4 b1 = *(const float4*)(bias + 8 * c + 4);
        float o0 = fmaxf(fmaf(a0, dv, b0.x), 0.f);
        float o1 = fmaxf(fmaf(a1, dv, b0.y), 0.f);
        float o2 = fmaxf(fmaf(a2, dv, b0.z), 0.f);
        float o3 = fmaxf(fmaf(a3, dv, b0.w), 0.f);
        float o4 = fmaxf(fmaf(a4, dv, b1.x), 0.f);
        float o5 = fmaxf(fmaf(a5, dv, b1.y), 0.f);
        float o6 = fmaxf(fmaf(a6, dv, b1.z), 0.f);
        float o7 = fmaxf(fmaf(a7, dv, b1.w), 0.f);
        uint4 o;
        o.x = (uint)f2bf(o0) | ((uint)f2bf(o1) << 16);
        o.y = (uint)f2bf(o2) | ((uint)f2bf(o3) << 16);
        o.z = (uint)f2bf(o4) | ((uint)f2bf(o5) << 16);
        o.w = (uint)f2bf(o6) | ((uint)f2bf(o7) << 16);
        ((uint4*)(Hout + (size_t)node * 128))[c] = o;
    }
}

// ---------------- layer-2 agg: eighth-wave uint2 fp8 gather, tail-split, sigmoid ----
// 8 edges per VMEM instruction (8 lanes x 8B = 64B row)
__global__ __launch_bounds__(256) void agg2_kernel(const uchar* __restrict__ Hs,
                                                   ushort* __restrict__ Z,
                                                   const int* __restrict__ rowptr,
                                                   const int* __restrict__ srcs,
                                                   const float* __restrict__ dinv,
                                                   const float* __restrict__ bias, int n) {
    int wv = __builtin_amdgcn_readfirstlane(threadIdx.x) >> 6;
    int lane = threadIdx.x & 63;
    int node = blockIdx.x * 4 + wv;
    if (node >= n) return;
    int o8 = lane >> 3, c = lane & 7;
    float dv = dinv[node];
    int start = rowptr[node], end = rowptr[node + 1];
    float a0 = 0.f, a1 = 0.f, a2 = 0.f, a3 = 0.f, a4 = 0.f, a5 = 0.f, a6 = 0.f, a7 = 0.f;
    if (o8 == 0) {
        uint2 s = ((const uint2*)(Hs + (size_t)node * 64))[c];
        f32x2 p0 = __builtin_amdgcn_cvt_pk_f32_fp8((int)s.x, false);
        f32x2 p1 = __builtin_amdgcn_cvt_pk_f32_fp8((int)s.x, true);
        f32x2 p2 = __builtin_amdgcn_cvt_pk_f32_fp8((int)s.y, false);
        f32x2 p3 = __builtin_amdgcn_cvt_pk_f32_fp8((int)s.y, true);
        a0 = p0[0]; a1 = p0[1]; a2 = p1[0]; a3 = p1[1];
        a4 = p2[0]; a5 = p2[1]; a6 = p3[0]; a7 = p3[1];
    }
    int deg = end - start;
    int full = start + (deg & ~7);
    for (int j = start; j < full; j += 8) {
        int sj = srcs[j + o8];
        uint2 v = ((const uint2*)(Hs + (size_t)sj * 64))[c];
        f32x2 p0 = __builtin_amdgcn_cvt_pk_f32_fp8((int)v.x, false);
        f32x2 p1 = __builtin_amdgcn_cvt_pk_f32_fp8((int)v.x, true);
        f32x2 p2 = __builtin_amdgcn_cvt_pk_f32_fp8((int)v.y, false);
        f32x2 p3 = __builtin_amdgcn_cvt_pk_f32_fp8((int)v.y, true);
        a0 += p0[0]; a1 += p0[1]; a2 += p1[0]; a3 += p1[1];
        a4 += p2[0]; a5 += p2[1]; a6 += p3[0]; a7 += p3[1];
    }
    if (deg & 7) {
        int jj = full + o8;
        int sj = srcs[min(jj, end - 1)];
        float w = (jj < end) ? 1.0f : 0.0f;
        uint2 v = ((const uint2*)(Hs + (size_t)sj * 64))[c];
        f32x2 p0 = __builtin_amdgcn_cvt_pk_f32_fp8((int)v.x, false);
        f32x2 p1 = __builtin_amdgcn_cvt_pk_f32_fp8((int)v.x, true);
        f32x2 p2 = __builtin_amdgcn_cvt_pk_f32_fp8((int)v.y, false);
        f32x2 p3 = __builtin_amdgcn_cvt_pk_f32_fp8((int)v.y, true);
        a0 = fmaf(w, p0[0], a0); a1 = fmaf(w, p0[1], a1);
        a2 = fmaf(w, p1[0], a2); a3 = fmaf(w, p1[1], a3);
        a4 = fmaf(w, p2[0], a4); a5 = fmaf(w, p2[1], a5);
        a6 = fmaf(w, p3[0], a6); a7 = fmaf(w, p3[1], a7);
    }
#pragma unroll
    for (int d = 8; d <= 32; d <<= 1) {
        a0 += __shfl_xor(a0, d); a1 += __shfl_xor(a1, d);
        a2 += __shfl_xor(a2, d); a3 += __shfl_xor(a3, d);
        a4 += __shfl_xor(a4, d); a5 += __shfl_xor(a5, d);
        a6 += __shfl_xor(a6, d); a7 += __shfl_xor(a7, d);
    }
    if (o8 == 0) {
        float4 b0 = *(const float4*)(bias + 8 * c);
        float4 b1 = *(const float4*)(bias + 8 * c + 4);
        float z0 = 1.0f / (1.0f + __expf(-fmaf(a0, dv, b0.x)));
        float z1 = 1.0f / (1.0f + __expf(-fmaf(a1, dv, b0.y)));
        float z2 = 1.0f / (1.0f + __expf(-fmaf(a2, dv, b0.z)));
        float z3 = 1.0f / (1.0f + __expf(-fmaf(a3, dv, b0.w)));
        float z4 = 1.0f / (1.0f + __expf(-fmaf(a4, dv, b1.x)));
        float z5 = 1.0f / (1.0f + __expf(-fmaf(a5, dv, b1.y)));
        float z6 = 1.0f / (1.0f + __expf(-fmaf(a6, dv, b1.z)));
        float z7 = 1.0f / (1.0f + __expf(-fmaf(a7, dv, b1.w)));
        uint4 o;
        o.x = (uint)f2bf(z0) | ((uint)f2bf(z1) << 16);
        o.y = (uint)f2bf(z2) | ((uint)f2bf(z3) << 16);
        o.z = (uint)f2bf(z4) | ((uint)f2bf(z5) << 16);
        o.w = (uint)f2bf(z6) | ((uint)f2bf(z7) << 16);
        ((uint4*)(Z + (size_t)node * 64))[c] = o;
    }
}

// ---------------- column mean over bf16 Z[n][64] ----------------
__global__ __launch_bounds__(256) void mean_kernel(const ushort* __restrict__ Z,
                                                   float* __restrict__ out,
                                                   int total, float inv_n) {
    __shared__ float s[256];
    int t = threadIdx.x;
    float acc = 0.0f;
    for (int i = blockIdx.x * 256 + t; i < total; i += gridDim.x * 256) acc += bf2f(Z[i]);
    s[t] = acc;
    __syncthreads();
    if (t < 64) {
        atomicAdd(&out[t], (s[t] + s[t + 64] + s[t + 128] + s[t + 192]) * inv_n);
    }
}

// ---------------- launch ----------------
extern "C" void kernel_launch(void* const* d_in, const int* in_sizes, int n_in,
                              void* d_out, int out_size, void* d_ws, size_t ws_size,
                              hipStream_t stream) {
    const float* x   = (const float*)d_in[0];
    const int*   ei  = (const int*)d_in[1];
    const float* W1  = (const float*)d_in[2];
    const float* bi1 = (const float*)d_in[3];
    const float* W2  = (const float*)d_in[4];
    const float* bi2 = (const float*)d_in[5];
    float* out = (float*)d_out;

    const int n = in_sizes[0] / IN_DIM;   // 100000
    const int E = in_sizes[1] / 2;        // 1600000
    const int* srcI = ei;
    const int* dstI = ei + E;

    // workspace carve (256B aligned)
    char* ws = (char*)d_ws;
    size_t off = 0;
    auto carve = [&](size_t bytes) {
        void* p = ws + off;
        off = (off + bytes + 255) & ~(size_t)255;
        return p;
    };
    const int nb     = (n + BKT - 1) / BKT;        // 391 buckets
    const int nbBin  = (E + CHUNK - 1) / CHUNK;    // 391 binning blocks
    const int nbGemm = (n / 16 + 3) / 4;           // 1563

    int*    blkhist    = (int*)carve((size_t)nbBin * nb * 4);   // ~611 KB
    int*    blkoff     = (int*)carve((size_t)nbBin * nb * 4);
    int*    bucket_off = (int*)carve((NBMAX + 1) * 4);
    int*    rowptr     = (int*)carve(((size_t)n + 1) * 4);
    float*  dinv       = (float*)carve((size_t)n * 4);
    int*    srcs       = (int*)carve((size_t)E * 4);
    uint*   pairs      = (uint*)carve((size_t)E * 4);
    ushort* W1p        = (ushort*)carve(128 * 128 * 2);
    ushort* W2p        = (ushort*)carve(128 * 64 * 2);
    uchar*  H1         = (uchar*)carve((size_t)n * 128);      // fp8 X@W1, prescaled in b4
    ushort* h1         = (ushort*)carve((size_t)n * 128 * 2); // bf16 relu output
    uchar*  H2s        = (uchar*)carve((size_t)n * 64);       // fp8, prescaled h1@W2
    ushort* Zb         = (ushort*)carve((size_t)n * 64 * 2);  // bf16 sigmoid output

    b1_kernel<<<nbBin + 96, 256, 0, stream>>>(dstI, blkhist, W1, W1p, W2, W2p,
                                              E, nb, nbBin);
    b2_kernel<<<1, 512, 0, stream>>>(blkhist, blkoff, bucket_off, out, nb, nbBin);
    b3_kernel<<<nbBin + nbGemm, 256, 0, stream>>>(srcI, dstI, blkoff, pairs,
                                                  x, W1p, H1, E, n, nb, nbBin);
    b4_kernel<<<nb, 256, 0, stream>>>(pairs, bucket_off, rowptr, dinv, srcs, H1, n, E, nb);

    agg1_kernel<<<(n + 3) / 4, 256, 0, stream>>>(H1, h1, rowptr, srcs, dinv, bi1, n);
    gemm2_kernel<<<nbGemm, 256, 0, stream>>>(h1, W2p, dinv, H2s, n);
    agg2_kernel<<<(n + 3) / 4, 256, 0, stream>>>(H2s, Zb, rowptr, srcs, dinv, bi2, n);
    mean_kernel<<<1024, 256, 0, stream>>>(Zb, out, n * OUT_DIM, 1.0f / (float)n);
}